// Round 1
// baseline (374.237 us; speedup 1.0000x reference)
//
#include <hip/hip_runtime.h>
#include <hip/hip_bf16.h>

#define B_      8
#define N_      8192
#define C_      64
#define CIN     67      // 3 + C
#define H1_     64
#define H2_     128
#define NS      32
#define NPOINT  2048
#define NGROUP  (B_ * NPOINT)          // 16384
#define NXYZ    (B_ * NPOINT * 3)      // 49152

// ---------------------------------------------------------------- new_xyz copy
__global__ __launch_bounds__(256) void copy_newxyz_kernel(
    const float* __restrict__ xyz, float* __restrict__ out)
{
    int i = blockIdx.x * 256 + threadIdx.x;
    if (i < NXYZ) {
        int b = i / (NPOINT * 3);
        int r = i - b * (NPOINT * 3);
        out[i] = xyz[(size_t)b * N_ * 3 + r];
    }
}

// ---------------------------------------------------------------- weight transpose
__global__ __launch_bounds__(256) void wtrans_kernel(
    const float* __restrict__ W1, const float* __restrict__ W2,
    float* __restrict__ W1T, float* __restrict__ W2T)
{
    int t = blockIdx.x * 256 + threadIdx.x;
    if (t < H1_ * CIN) { int o = t / CIN;  int c = t - o * CIN;  W1T[c * H1_ + o] = W1[t]; }
    if (t < H2_ * H1_) { int o = t / H1_;  int c = t - o * H1_;  W2T[c * H2_ + o] = W2[t]; }
}

// ---------------------------------------------------------------- features (B,C,N) -> (B,N,C)
__global__ __launch_bounds__(256) void ftrans_kernel(
    const float* __restrict__ f, float* __restrict__ fT)
{
    __shared__ float tile[64][65];
    int bidx = blockIdx.x;              // b*128 + ntile
    int b = bidx >> 7, nt = bidx & 127;
    int n0 = nt * 64;
    int tx = threadIdx.x & 63, ty = threadIdx.x >> 6;
    const float* src = f + (size_t)b * C_ * N_;
#pragma unroll
    for (int k = 0; k < 16; ++k) {
        int c = ty * 16 + k;
        tile[c][tx] = src[(size_t)c * N_ + n0 + tx];
    }
    __syncthreads();
    float* dst = fT + ((size_t)b * N_ + n0) * C_;
#pragma unroll
    for (int k = 0; k < 16; ++k) {
        int n = ty * 16 + k;
        dst[(size_t)n * C_ + tx] = tile[tx][n];
    }
}

// ---------------------------------------------------------------- ball query (wave per query)
// Emits the up-to-32 smallest in-ball indices in ascending order, fills the
// rest with the first index — bit-exact match of the reference's argsort trick.
__global__ __launch_bounds__(256) void ballq_kernel(
    const float* __restrict__ xyz, int* __restrict__ idx)
{
    int wq = blockIdx.x * 4 + (threadIdx.x >> 6);   // query id, < 16384
    int lane = threadIdx.x & 63;
    int b = wq >> 11, s = wq & 2047;
    const float* base = xyz + (size_t)b * N_ * 3;
    float qx = base[s * 3 + 0], qy = base[s * 3 + 1], qz = base[s * 3 + 2];
    // f32(0.1(f64)*0.1(f64)) == 0.01f. NOT 0.1f*0.1f (rounds differently!)
    const float r2 = 0.01f;
    unsigned long long lmask = (1ull << lane) - 1ull;
    int cnt = 0;
    int first = -1;
    int* myidx = idx + (size_t)wq * NS;
    for (int ch = 0; ch < N_ / 64; ++ch) {
        int jj = ch * 64 + lane;
        const float* p = base + (size_t)jj * 3;
        // exact reference arithmetic: no FMA contraction, (dx^2+dy^2)+dz^2
        float dx = __fsub_rn(p[0], qx);
        float dy = __fsub_rn(p[1], qy);
        float dz = __fsub_rn(p[2], qz);
        float d2 = __fadd_rn(__fadd_rn(__fmul_rn(dx, dx), __fmul_rn(dy, dy)),
                             __fmul_rn(dz, dz));
        bool pred = d2 < r2;
        unsigned long long m = __ballot(pred);
        if (first < 0 && m != 0ull) first = ch * 64 + __builtin_ctzll(m);
        if (pred) {
            int pos = cnt + __builtin_popcountll(m & lmask);
            if (pos < NS) myidx[pos] = jj;
        }
        cnt += __builtin_popcountll(m);
        if (cnt >= NS) break;
    }
    if (cnt < NS) {
        int f0 = (first < 0) ? s : first;   // count>=1 always (self in ball)
        if (lane < NS - cnt) myidx[cnt + lane] = f0;
    }
}

// ---------------------------------------------------------------- fused gather + MLP + maxpool
// Block = 256 threads = 4 waves, processes 2 groups (gg = lane>>5 picks group).
// Wave w owns L1 outputs [16w,16w+16) and L2 outputs [32w,32w+32); weight reads
// are wave-uniform -> s_load (scalar pipe), VALU does only FMAs.
template <bool USE_FT>
__global__ __launch_bounds__(256) void mlp_kernel(
    const float* __restrict__ xyz,
    const float* __restrict__ feat,      // (B,C,N)
    const float* __restrict__ fT,        // (B,N,C), valid if USE_FT
    const float* __restrict__ W1T,       // (CIN,H1)
    const float* __restrict__ b1,
    const float* __restrict__ W2T,       // (H1,H2)
    const float* __restrict__ b2,
    const int*   __restrict__ idx,
    float* __restrict__ out)
{
    __shared__ float grouped[2][CIN][NS + 1];
    __shared__ float h1s[2][H1_][NS + 1];
    __shared__ int   sidx[2][NS];

    int pair = blockIdx.x;
    int t = threadIdx.x;

    if (t < 64) {
        int gg = t >> 5, j = t & 31;
        sidx[gg][j] = idx[(size_t)(pair * 2 + gg) * NS + j];
    }
    __syncthreads();

    // ---- gather: thread = (gg, q, j)
    {
        int gg = t >> 7;
        int t2 = t & 127;
        int j = t2 & 31;
        int q = t2 >> 5;       // 0..3
        int g = pair * 2 + gg;
        int b = g >> 11, s = g & 2047;
        int ij = sidx[gg][j];
        if (USE_FT) {
            const float4* src = reinterpret_cast<const float4*>(
                fT + ((size_t)b * N_ + ij) * C_);
#pragma unroll
            for (int k = 0; k < 4; ++k) {
                float4 v = src[q * 4 + k];
                int c = (q * 4 + k) * 4;
                grouped[gg][3 + c + 0][j] = v.x;
                grouped[gg][3 + c + 1][j] = v.y;
                grouped[gg][3 + c + 2][j] = v.z;
                grouped[gg][3 + c + 3][j] = v.w;
            }
        } else {
#pragma unroll
            for (int k = 0; k < 16; ++k) {
                int c = q * 16 + k;
                grouped[gg][3 + c][j] = feat[((size_t)b * C_ + c) * N_ + ij];
            }
        }
        if (q == 0) {
            const float* pj = xyz + ((size_t)b * N_ + ij) * 3;
            const float* ps = xyz + ((size_t)b * N_ + s) * 3;
            grouped[gg][0][j] = pj[0] - ps[0];
            grouped[gg][1][j] = pj[1] - ps[1];
            grouped[gg][2][j] = pj[2] - ps[2];
        }
    }
    __syncthreads();

    int w = __builtin_amdgcn_readfirstlane(t >> 6);  // wave id, forced scalar
    int lane = t & 63;
    int gg = lane >> 5, j = lane & 31;

    // ---- layer 1: o in [16w, 16w+16)
    {
        int o0 = w * 16;
        float acc[16];
#pragma unroll
        for (int k = 0; k < 16; ++k) acc[k] = b1[o0 + k];
        for (int c = 0; c < CIN; ++c) {
            float v = grouped[gg][c][j];
#pragma unroll
            for (int k = 0; k < 16; ++k)
                acc[k] = fmaf(W1T[c * H1_ + o0 + k], v, acc[k]);
        }
#pragma unroll
        for (int k = 0; k < 16; ++k) h1s[gg][o0 + k][j] = fmaxf(acc[k], 0.f);
    }
    __syncthreads();

    // ---- layer 2 + relu + maxpool: o in [32w, 32w+32)
    {
        int o0 = w * 32;
        float acc[32];
#pragma unroll
        for (int k = 0; k < 32; ++k) acc[k] = b2[o0 + k];
        for (int c = 0; c < H1_; ++c) {
            float v = h1s[gg][c][j];
#pragma unroll
            for (int k = 0; k < 32; ++k)
                acc[k] = fmaf(W2T[c * H2_ + o0 + k], v, acc[k]);
        }
#pragma unroll
        for (int k = 0; k < 32; ++k) {
            float r = fmaxf(acc[k], 0.f);
#pragma unroll
            for (int m = 16; m >= 1; m >>= 1) r = fmaxf(r, __shfl_xor(r, m));
            acc[k] = r;
        }
        if (j == 0) {
            int g = pair * 2 + gg;
            int b = g >> 11, s = g & 2047;
#pragma unroll
            for (int k = 0; k < 32; ++k)
                out[NXYZ + ((size_t)b * H2_ + o0 + k) * NPOINT + s] = acc[k];
        }
    }
}

// ---------------------------------------------------------------- launcher
extern "C" void kernel_launch(void* const* d_in, const int* in_sizes, int n_in,
                              void* d_out, int out_size, void* d_ws, size_t ws_size,
                              hipStream_t stream)
{
    const float* xyz  = (const float*)d_in[0];
    const float* feat = (const float*)d_in[1];
    const float* W1   = (const float*)d_in[2];
    const float* b1   = (const float*)d_in[3];
    const float* W2   = (const float*)d_in[4];
    const float* b2   = (const float*)d_in[5];
    float* out = (float*)d_out;

    char* ws = (char*)d_ws;
    int*   idxbuf = (int*)ws;                                  // 16384*32*4 = 2 MiB
    float* W1T = (float*)(ws + (2u << 20));                    // 17152 B
    float* W2T = (float*)(ws + (2u << 20) + 0x8000);           // 32768 B
    float* fT  = (float*)(ws + (2u << 20) + 0x8000 + 0x10000); // 16 MiB
    size_t need_ft = (size_t)(2u << 20) + 0x8000 + 0x10000 + (size_t)B_ * N_ * C_ * 4;
    bool use_ft = (ws_size >= need_ft);   // constant across calls -> capture-safe

    copy_newxyz_kernel<<<(NXYZ + 255) / 256, 256, 0, stream>>>(xyz, out);
    wtrans_kernel<<<(H2_ * H1_ + 255) / 256, 256, 0, stream>>>(W1, W2, W1T, W2T);
    if (use_ft)
        ftrans_kernel<<<B_ * (N_ / 64), 256, 0, stream>>>(feat, fT);
    ballq_kernel<<<NGROUP / 4, 256, 0, stream>>>(xyz, idxbuf);
    if (use_ft)
        mlp_kernel<true><<<NGROUP / 2, 256, 0, stream>>>(xyz, feat, fT, W1T, b1, W2T, b2, idxbuf, out);
    else
        mlp_kernel<false><<<NGROUP / 2, 256, 0, stream>>>(xyz, feat, fT, W1T, b1, W2T, b2, idxbuf, out);
}

// Round 3
// 292.545 us; speedup vs baseline: 1.2792x; 1.2792x over previous
//
#include <hip/hip_runtime.h>
#include <hip/hip_bf16.h>

#define B_      8
#define N_      8192
#define C_      64
#define H1_     64
#define H2_     128
#define NS      32
#define NPOINT  2048
#define NGROUP  (B_ * NPOINT)          // 16384
#define NXYZ    (B_ * NPOINT * 3)      // 49152
#define K1P     96                     // L1 K padded: 64 feat + 3 rel + 29 zero

typedef short bf16x8 __attribute__((ext_vector_type(8)));
typedef float f32x4  __attribute__((ext_vector_type(4)));
typedef unsigned short u16x4 __attribute__((ext_vector_type(4)));

#define MFMA16 __builtin_amdgcn_mfma_f32_16x16x32_bf16

__device__ inline unsigned short f2bf(float f) {
    unsigned u = __builtin_bit_cast(unsigned, f);
    return (unsigned short)((u + 0x7FFF + ((u >> 16) & 1)) >> 16);
}
__device__ inline float bf2f(unsigned short h) {
    unsigned u = ((unsigned)h) << 16;
    return __builtin_bit_cast(float, u);
}

// ---------------------------------------------------------------- new_xyz copy
__global__ __launch_bounds__(256) void copy_newxyz_kernel(
    const float* __restrict__ xyz, float* __restrict__ out)
{
    int i = blockIdx.x * 256 + threadIdx.x;
    if (i < NXYZ) {
        int b = i / (NPOINT * 3);
        int r = i - b * (NPOINT * 3);
        out[i] = xyz[(size_t)b * N_ * 3 + r];
    }
}

// ---------------------------------------------------------------- weight prep (hi/lo bf16 split)
// W1p: [64 o][96 k]  k<64 -> feature col 3+k ; 64..66 -> rel cols 0..2 ; else 0
// W2p: [128 o][64 k]
__global__ __launch_bounds__(256) void prep_kernel(
    const float* __restrict__ W1, const float* __restrict__ W2,
    unsigned short* __restrict__ W1p_hi, unsigned short* __restrict__ W1p_lo,
    unsigned short* __restrict__ W2p_hi, unsigned short* __restrict__ W2p_lo)
{
    int t = blockIdx.x * 256 + threadIdx.x;
    if (t < H1_ * K1P) {
        int o = t / K1P, k = t - o * K1P;
        float w = 0.f;
        if (k < 64) w = W1[o * 67 + 3 + k];
        else if (k < 67) w = W1[o * 67 + (k - 64)];
        unsigned short h = f2bf(w);
        W1p_hi[t] = h;
        W1p_lo[t] = f2bf(w - bf2f(h));
    }
    if (t < H2_ * H1_) {
        float w = W2[t];
        unsigned short h = f2bf(w);
        W2p_hi[t] = h;
        W2p_lo[t] = f2bf(w - bf2f(h));
    }
}

// ---------------------------------------------------------------- features (B,C,N) f32 -> (B,N,C) bf16 hi/lo
__global__ __launch_bounds__(256) void ftrans_kernel(
    const float* __restrict__ f,
    unsigned short* __restrict__ hi, unsigned short* __restrict__ lo)
{
    __shared__ float tile[64][65];
    int bidx = blockIdx.x;              // b*128 + ntile
    int b = bidx >> 7, nt = bidx & 127;
    int n0 = nt * 64;
    int tx = threadIdx.x & 63, ty = threadIdx.x >> 6;
#pragma unroll
    for (int k = 0; k < 16; ++k) {
        int c = ty * 16 + k;
        tile[c][tx] = f[((size_t)b * C_ + c) * N_ + n0 + tx];
    }
    __syncthreads();
#pragma unroll
    for (int k = 0; k < 16; ++k) {
        int n = ty * 16 + k;
        float v = tile[tx][n];
        unsigned short h = f2bf(v);
        size_t dst = ((size_t)(b * N_ + n0 + n)) * C_ + tx;
        hi[dst] = h;
        lo[dst] = f2bf(v - bf2f(h));
    }
}

// ---------------------------------------------------------------- ball query, LDS-staged
// 4 waves/block = 4 queries share staged xyz chunks (all same batch b).
__global__ __launch_bounds__(256) void ballq_kernel(
    const float* __restrict__ xyz, int* __restrict__ idx)
{
    __shared__ float pts[2048 * 3];
    int t = threadIdx.x;
    int w = t >> 6, lane = t & 63;
    int wq = blockIdx.x * 4 + w;
    int b = wq >> 11, s = wq & 2047;
    const float* base = xyz + (size_t)b * N_ * 3;
    float qx = base[s * 3 + 0], qy = base[s * 3 + 1], qz = base[s * 3 + 2];
    const float r2 = 0.01f;   // f32(0.1(f64)^2) == 0.01f exactly; NOT 0.1f*0.1f
    unsigned long long lmask = (1ull << lane) - 1ull;
    int cnt = 0, first = -1;
    int* myidx = idx + (size_t)wq * NS;

    for (int c = 0; c < N_ / 2048; ++c) {
        __syncthreads();
        const float4* src = reinterpret_cast<const float4*>(base + c * 6144);
        float4* dst = reinterpret_cast<float4*>(pts);
#pragma unroll
        for (int k = 0; k < 6; ++k) dst[k * 256 + t] = src[k * 256 + t];
        __syncthreads();
        if (cnt < NS) {
            for (int sub = 0; sub < 32; ++sub) {
                int jl = sub * 64 + lane;
                // bit-exact reference arithmetic: no FMA, (dx^2+dy^2)+dz^2
                float dx = __fsub_rn(pts[jl * 3 + 0], qx);
                float dy = __fsub_rn(pts[jl * 3 + 1], qy);
                float dz = __fsub_rn(pts[jl * 3 + 2], qz);
                float d2 = __fadd_rn(__fadd_rn(__fmul_rn(dx, dx), __fmul_rn(dy, dy)),
                                     __fmul_rn(dz, dz));
                bool pred = d2 < r2;
                unsigned long long m = __ballot(pred);
                if (first < 0 && m != 0ull) first = c * 2048 + sub * 64 + __builtin_ctzll(m);
                if (pred) {
                    int pos = cnt + __builtin_popcountll(m & lmask);
                    if (pos < NS) myidx[pos] = c * 2048 + jl;
                }
                cnt += __builtin_popcountll(m);
                if (cnt >= NS) break;
            }
        }
    }
    if (cnt < NS) {
        int f0 = (first < 0) ? s : first;
        if (lane < NS - cnt) myidx[cnt + lane] = f0;
    }
}

// ---------------------------------------------------------------- fused gather + MLP + maxpool (MFMA)
// Wave per group, 4 groups/block, no __syncthreads.
// 16x16x32 bf16 MFMA layouts: A[row=l&15][k=8*(l>>4)+j], B[k=8*(l>>4)+j][col=l&15],
// D[row=(l>>4)*4+r][col=l&15]  (m89-verified C/D).
// Split precision: acc += Ah*Bh + Ah*Bl + Al*Bh  (rel k-tile: Ah*Bh only, values ~0.1).
__global__ __launch_bounds__(256) void mlp_mfma_kernel(
    const float* __restrict__ xyz,
    const unsigned short* __restrict__ fT_hi, const unsigned short* __restrict__ fT_lo,
    const unsigned short* __restrict__ W1p_hi, const unsigned short* __restrict__ W1p_lo,
    const float* __restrict__ b1,
    const unsigned short* __restrict__ W2p_hi, const unsigned short* __restrict__ W2p_lo,
    const float* __restrict__ b2,
    const int* __restrict__ idx,
    float* __restrict__ Ytmp)          // (B,S,128) f32
{
    __shared__ unsigned short Hs[4][2][32][72];   // [wave][hi/lo][sample][o pad 72] = 36 KiB
    int t = threadIdx.x;
    int w = t >> 6, lane = t & 63;
    int g = blockIdx.x * 4 + w;
    int b = g >> 11, s = g & 2047;
    int cl = lane & 15, kq = lane >> 4;

    // two sample columns per lane (nt=0: cols 0..15, nt=1: cols 16..31)
    int i0 = idx[(size_t)g * NS + cl];
    int i1 = idx[(size_t)g * NS + 16 + cl];

    // ---- B fragments: features, hi/lo, 2 k-tiles x 2 n-tiles
    bf16x8 bh[2][2], bl[2][2];
#pragma unroll
    for (int nt = 0; nt < 2; ++nt) {
        int i = nt ? i1 : i0;
        size_t rowoff = ((size_t)(b * N_ + i)) * C_ + kq * 8;
#pragma unroll
        for (int kt = 0; kt < 2; ++kt) {
            bh[nt][kt] = *reinterpret_cast<const bf16x8*>(fT_hi + rowoff + kt * 32);
            bl[nt][kt] = *reinterpret_cast<const bf16x8*>(fT_lo + rowoff + kt * 32);
        }
    }
    // ---- rel k-tile B fragment (k 64..66 live, rest zero; only kq==0 lanes carry data)
    const float* qp = xyz + ((size_t)(b * N_) + s) * 3;
    float qx = qp[0], qy = qp[1], qz = qp[2];
    bf16x8 brel[2];
#pragma unroll
    for (int nt = 0; nt < 2; ++nt) {
        int i = nt ? i1 : i0;
        bf16x8 v = (bf16x8)(short)0;
        if (kq == 0) {
            const float* p = xyz + ((size_t)(b * N_) + i) * 3;
            v[0] = (short)f2bf(__fsub_rn(p[0], qx));
            v[1] = (short)f2bf(__fsub_rn(p[1], qy));
            v[2] = (short)f2bf(__fsub_rn(p[2], qz));
        }
        brel[nt] = v;
    }

    // ---- Layer 1: H(64x32) = W1(64x96) * X(96x32)
    f32x4 acc[8];   // [mt][nt]
#pragma unroll
    for (int mt = 0; mt < 4; ++mt) {
        f32x4 bias = *reinterpret_cast<const f32x4*>(b1 + mt * 16 + kq * 4);
        acc[mt * 2 + 0] = bias;
        acc[mt * 2 + 1] = bias;
    }
#pragma unroll
    for (int mt = 0; mt < 4; ++mt) {
        const unsigned short* wh = W1p_hi + (size_t)(mt * 16 + cl) * K1P + kq * 8;
        const unsigned short* wl = W1p_lo + (size_t)(mt * 16 + cl) * K1P + kq * 8;
        bf16x8 ah0 = *reinterpret_cast<const bf16x8*>(wh);
        bf16x8 ah1 = *reinterpret_cast<const bf16x8*>(wh + 32);
        bf16x8 ah2 = *reinterpret_cast<const bf16x8*>(wh + 64);
        bf16x8 al0 = *reinterpret_cast<const bf16x8*>(wl);
        bf16x8 al1 = *reinterpret_cast<const bf16x8*>(wl + 32);
#pragma unroll
        for (int nt = 0; nt < 2; ++nt) {
            f32x4 a = acc[mt * 2 + nt];
            a = MFMA16(ah0, bh[nt][0], a, 0, 0, 0);
            a = MFMA16(ah0, bl[nt][0], a, 0, 0, 0);
            a = MFMA16(al0, bh[nt][0], a, 0, 0, 0);
            a = MFMA16(ah1, bh[nt][1], a, 0, 0, 0);
            a = MFMA16(ah1, bl[nt][1], a, 0, 0, 0);
            a = MFMA16(al1, bh[nt][1], a, 0, 0, 0);
            a = MFMA16(ah2, brel[nt], a, 0, 0, 0);
            acc[mt * 2 + nt] = a;
        }
    }

    // ---- relu + hi/lo split -> LDS (same-wave round trip, no barrier needed)
#pragma unroll
    for (int mt = 0; mt < 4; ++mt) {
#pragma unroll
        for (int nt = 0; nt < 2; ++nt) {
            f32x4 v = acc[mt * 2 + nt];
            u16x4 hh, hl;
#pragma unroll
            for (int r = 0; r < 4; ++r) {
                float h = fmaxf(v[r], 0.f);
                unsigned short hb = f2bf(h);
                hh[r] = hb;
                hl[r] = f2bf(h - bf2f(hb));
            }
            *reinterpret_cast<u16x4*>(&Hs[w][0][nt * 16 + cl][mt * 16 + kq * 4]) = hh;
            *reinterpret_cast<u16x4*>(&Hs[w][1][nt * 16 + cl][mt * 16 + kq * 4]) = hl;
        }
    }

    // ---- Layer 2: Y(128x32) = W2(128x64) * H(64x32)
    bf16x8 hbh[2][2], hbl[2][2];
#pragma unroll
    for (int nt = 0; nt < 2; ++nt)
#pragma unroll
        for (int kt = 0; kt < 2; ++kt) {
            hbh[nt][kt] = *reinterpret_cast<const bf16x8*>(&Hs[w][0][nt * 16 + cl][kt * 32 + kq * 8]);
            hbl[nt][kt] = *reinterpret_cast<const bf16x8*>(&Hs[w][1][nt * 16 + cl][kt * 32 + kq * 8]);
        }
    f32x4 acc2[16];  // [mt][nt], mt=0..7
#pragma unroll
    for (int mt = 0; mt < 8; ++mt) {
        f32x4 bias = *reinterpret_cast<const f32x4*>(b2 + mt * 16 + kq * 4);
        acc2[mt * 2 + 0] = bias;
        acc2[mt * 2 + 1] = bias;
    }
#pragma unroll
    for (int mt = 0; mt < 8; ++mt) {
        const unsigned short* wh = W2p_hi + (size_t)(mt * 16 + cl) * H1_ + kq * 8;
        const unsigned short* wl = W2p_lo + (size_t)(mt * 16 + cl) * H1_ + kq * 8;
        bf16x8 ah0 = *reinterpret_cast<const bf16x8*>(wh);
        bf16x8 ah1 = *reinterpret_cast<const bf16x8*>(wh + 32);
        bf16x8 al0 = *reinterpret_cast<const bf16x8*>(wl);
        bf16x8 al1 = *reinterpret_cast<const bf16x8*>(wl + 32);
#pragma unroll
        for (int nt = 0; nt < 2; ++nt) {
            f32x4 a = acc2[mt * 2 + nt];
            a = MFMA16(ah0, hbh[nt][0], a, 0, 0, 0);
            a = MFMA16(ah0, hbl[nt][0], a, 0, 0, 0);
            a = MFMA16(al0, hbh[nt][0], a, 0, 0, 0);
            a = MFMA16(ah1, hbh[nt][1], a, 0, 0, 0);
            a = MFMA16(ah1, hbl[nt][1], a, 0, 0, 0);
            a = MFMA16(al1, hbh[nt][1], a, 0, 0, 0);
            acc2[mt * 2 + nt] = a;
        }
    }

    // ---- relu + maxpool over 32 samples + store (coalesced float4, lanes cl==0)
#pragma unroll
    for (int mt = 0; mt < 8; ++mt) {
        f32x4 m;
#pragma unroll
        for (int r = 0; r < 4; ++r)
            m[r] = fmaxf(fmaxf(acc2[mt * 2 + 0][r], 0.f), fmaxf(acc2[mt * 2 + 1][r], 0.f));
#pragma unroll
        for (int mask = 1; mask <= 8; mask <<= 1)
#pragma unroll
            for (int r = 0; r < 4; ++r)
                m[r] = fmaxf(m[r], __shfl_xor(m[r], mask));
        if (cl == 0)
            *reinterpret_cast<f32x4*>(Ytmp + (size_t)g * H2_ + mt * 16 + kq * 4) = m;
    }
}

// ---------------------------------------------------------------- Ytmp (B,S,128) -> out (B,128,S)
__global__ __launch_bounds__(256) void ytrans_kernel(
    const float* __restrict__ Y, float* __restrict__ out)
{
    __shared__ float tile[64][65];
    int blk = blockIdx.x;                   // b*64 + st*2 + ot
    int b = blk >> 6, r = blk & 63;
    int st = r >> 1, ot = r & 1;
    int s0 = st * 64, o0 = ot * 64;
    int j = threadIdx.x & 63, i4 = threadIdx.x >> 6;
#pragma unroll
    for (int k = 0; k < 16; ++k) {
        int i = i4 * 16 + k;
        tile[i][j] = Y[((size_t)(b * NPOINT + s0 + i)) * H2_ + o0 + j];
    }
    __syncthreads();
#pragma unroll
    for (int k = 0; k < 16; ++k) {
        int i = i4 * 16 + k;
        out[NXYZ + ((size_t)(b * H2_ + o0 + i)) * NPOINT + s0 + j] = tile[j][i];
    }
}

// ---------------------------------------------------------------- launcher
extern "C" void kernel_launch(void* const* d_in, const int* in_sizes, int n_in,
                              void* d_out, int out_size, void* d_ws, size_t ws_size,
                              hipStream_t stream)
{
    const float* xyz  = (const float*)d_in[0];
    const float* feat = (const float*)d_in[1];
    const float* W1   = (const float*)d_in[2];
    const float* b1   = (const float*)d_in[3];
    const float* W2   = (const float*)d_in[4];
    const float* b2   = (const float*)d_in[5];
    float* out = (float*)d_out;

    char* ws = (char*)d_ws;
    size_t off = 0;
    int* idxbuf = (int*)(ws + off);               off += (size_t)NGROUP * NS * 4;       // 2 MiB
    unsigned short* W1p_hi = (unsigned short*)(ws + off); off += H1_ * K1P * 2;
    unsigned short* W1p_lo = (unsigned short*)(ws + off); off += H1_ * K1P * 2;
    unsigned short* W2p_hi = (unsigned short*)(ws + off); off += H2_ * H1_ * 2;
    unsigned short* W2p_lo = (unsigned short*)(ws + off); off += H2_ * H1_ * 2;
    off = (off + 255) & ~(size_t)255;
    unsigned short* fT_hi = (unsigned short*)(ws + off);  off += (size_t)B_ * N_ * C_ * 2; // 8 MiB
    unsigned short* fT_lo = (unsigned short*)(ws + off);  off += (size_t)B_ * N_ * C_ * 2; // 8 MiB
    float* Ytmp = (float*)(ws + off);             off += (size_t)NGROUP * H2_ * 4;      // 8 MiB

    copy_newxyz_kernel<<<(NXYZ + 255) / 256, 256, 0, stream>>>(xyz, out);
    prep_kernel<<<32, 256, 0, stream>>>(W1, W2, W1p_hi, W1p_lo, W2p_hi, W2p_lo);
    ftrans_kernel<<<B_ * (N_ / 64), 256, 0, stream>>>(feat, fT_hi, fT_lo);
    ballq_kernel<<<NGROUP / 4, 256, 0, stream>>>(xyz, idxbuf);
    mlp_mfma_kernel<<<NGROUP / 4, 256, 0, stream>>>(
        xyz, fT_hi, fT_lo, W1p_hi, W1p_lo, b1, W2p_hi, W2p_lo, b2, idxbuf, Ytmp);
    ytrans_kernel<<<B_ * 64, 256, 0, stream>>>(Ytmp, out);
}

// Round 4
// 191.319 us; speedup vs baseline: 1.9561x; 1.5291x over previous
//
#include <hip/hip_runtime.h>
#include <hip/hip_bf16.h>

#define B_      8
#define N_      8192
#define C_      64
#define H1_     64
#define H2_     128
#define NS      32
#define NPOINT  2048
#define NGROUP  (B_ * NPOINT)          // 16384
#define NXYZ    (B_ * NPOINT * 3)      // 49152
#define GD      10
#define NCP     1024                   // padded cell count (1000 used)

typedef short bf16x8 __attribute__((ext_vector_type(8)));
typedef short bf16x4 __attribute__((ext_vector_type(4)));
typedef float f32x4  __attribute__((ext_vector_type(4)));

#define MFMA32 __builtin_amdgcn_mfma_f32_16x16x32_bf16
#define MFMA16 __builtin_amdgcn_mfma_f32_16x16x16bf16_1k

__device__ inline unsigned short f2bf(float f) {
    unsigned u = __builtin_bit_cast(unsigned, f);
    return (unsigned short)((u + 0x7FFF + ((u >> 16) & 1)) >> 16);
}
__device__ inline float bf2f(unsigned short h) {
    unsigned u = ((unsigned)h) << 16;
    return __builtin_bit_cast(float, u);
}

// ---------------------------------------------------------------- new_xyz copy
__global__ __launch_bounds__(256) void copy_newxyz_kernel(
    const float* __restrict__ xyz, float* __restrict__ out)
{
    int i = blockIdx.x * 256 + threadIdx.x;
    if (i < NXYZ) {
        int b = i / (NPOINT * 3);
        int r = i - b * (NPOINT * 3);
        out[i] = xyz[(size_t)b * N_ * 3 + r];
    }
}

// ---------------------------------------------------------------- weight prep (hi/lo, MFMA-permuted)
// W1x[(mt*3+kt)*512 + lane*8 + j]  <- W1split[row=mt*16+(lane&15)][k=kt*32+(lane>>4)*8+j]
//   W1split[row][k]: k<64 -> W1[row][3+k]; 64..66 -> W1[row][k-64]; else 0
// W2x[(mt*2+kt2p)*512 + lane*8 + half*4+i] <- W2[row=mt*16+(lane&15)][k=kt2p*32+half*16+(lane>>4)*4+i]
__global__ __launch_bounds__(256) void prep_kernel(
    const float* __restrict__ W1, const float* __restrict__ W2,
    unsigned short* __restrict__ W1x_hi, unsigned short* __restrict__ W1x_lo,
    unsigned short* __restrict__ W2x_hi, unsigned short* __restrict__ W2x_lo)
{
    int t = blockIdx.x * 256 + threadIdx.x;
    if (t < 6144) {
        int j = t & 7, cl = (t >> 3) & 15, kq = (t >> 7) & 3, t2 = t >> 9;
        int kt = t2 % 3, mt = t2 / 3;
        int row = mt * 16 + cl, k = kt * 32 + kq * 8 + j;
        float wv = 0.f;
        if (k < 64) wv = W1[row * 67 + 3 + k];
        else if (k < 67) wv = W1[row * 67 + (k - 64)];
        unsigned short h = f2bf(wv);
        W1x_hi[t] = h; W1x_lo[t] = f2bf(wv - bf2f(h));
    }
    if (t < 8192) {
        int i = t & 3, half = (t >> 2) & 1, cl = (t >> 3) & 15;
        int kq = (t >> 7) & 3, kt2p = (t >> 9) & 1, mt = t >> 10;
        int row = mt * 16 + cl, k = kt2p * 32 + half * 16 + kq * 4 + i;
        float wv = W2[row * 64 + k];
        unsigned short h = f2bf(wv);
        W2x_hi[t] = h; W2x_lo[t] = f2bf(wv - bf2f(h));
    }
}

// ---------------------------------------------------------------- features (B,C,N) f32 -> (B,N,C) bf16 hi/lo
__global__ __launch_bounds__(256) void ftrans_kernel(
    const float* __restrict__ f,
    unsigned short* __restrict__ hi, unsigned short* __restrict__ lo)
{
    __shared__ float tile[64][65];
    int bidx = blockIdx.x;
    int b = bidx >> 7, nt = bidx & 127;
    int n0 = nt * 64;
    int tx = threadIdx.x & 63, ty = threadIdx.x >> 6;
#pragma unroll
    for (int k = 0; k < 16; ++k) {
        int c = ty * 16 + k;
        tile[c][tx] = f[((size_t)b * C_ + c) * N_ + n0 + tx];
    }
    __syncthreads();
#pragma unroll
    for (int k = 0; k < 16; ++k) {
        int n = ty * 16 + k;
        float v = tile[tx][n];
        unsigned short h = f2bf(v);
        size_t dst = ((size_t)(b * N_ + n0 + n)) * C_ + tx;
        hi[dst] = h;
        lo[dst] = f2bf(v - bf2f(h));
    }
}

// ---------------------------------------------------------------- grid build (counting sort by cell)
// cell = (int)(x*9.999f): cell size ~0.1 with margin so dist<0.1 => |dcell|<=1 per dim.
__global__ __launch_bounds__(256) void gridbuild_kernel(
    const float* __restrict__ xyz,
    int* __restrict__ cellStart,     // [B][NCP+1]
    int* __restrict__ sortedId,      // [B][N]
    float* __restrict__ sortedXyz)   // [B][N][3]
{
    __shared__ int hist[NCP];
    __shared__ int wsum[4];
    int b = blockIdx.x, t = threadIdx.x;
    for (int i = t; i < NCP; i += 256) hist[i] = 0;
    __syncthreads();
    const float* base = xyz + (size_t)b * N_ * 3;
    for (int k = 0; k < N_ / 256; ++k) {
        int i = k * 256 + t;
        float x = base[i * 3], y = base[i * 3 + 1], z = base[i * 3 + 2];
        int c = (((int)(x * 9.999f)) * GD + (int)(y * 9.999f)) * GD + (int)(z * 9.999f);
        atomicAdd(&hist[c], 1);
    }
    __syncthreads();
    int h0 = hist[t * 4], h1 = hist[t * 4 + 1], h2 = hist[t * 4 + 2], h3 = hist[t * 4 + 3];
    int s = h0 + h1 + h2 + h3;
    int lane = t & 63, w = t >> 6;
    int v = s;
    for (int d = 1; d < 64; d <<= 1) {
        int o = __shfl_up(v, d);
        if (lane >= d) v += o;
    }
    if (lane == 63) wsum[w] = v;
    __syncthreads();
    int wofs = 0;
    for (int i = 0; i < 4; ++i) wofs += (i < w) ? wsum[i] : 0;
    int excl = wofs + v - s;
    int* cs = cellStart + b * (NCP + 1);
    cs[t * 4]     = excl;
    cs[t * 4 + 1] = excl + h0;
    cs[t * 4 + 2] = excl + h0 + h1;
    cs[t * 4 + 3] = excl + h0 + h1 + h2;
    if (t == 255) cs[NCP] = excl + s;
    __syncthreads();
    hist[t * 4] = excl; hist[t * 4 + 1] = excl + h0;
    hist[t * 4 + 2] = excl + h0 + h1; hist[t * 4 + 3] = excl + h0 + h1 + h2;
    __syncthreads();
    for (int k = 0; k < N_ / 256; ++k) {
        int i = k * 256 + t;
        float x = base[i * 3], y = base[i * 3 + 1], z = base[i * 3 + 2];
        int c = (((int)(x * 9.999f)) * GD + (int)(y * 9.999f)) * GD + (int)(z * 9.999f);
        int pos = atomicAdd(&hist[c], 1);
        sortedId[b * N_ + pos] = i;
        float* d = sortedXyz + ((size_t)(b * N_) + pos) * 3;
        d[0] = x; d[1] = y; d[2] = z;
    }
}

// ---------------------------------------------------------------- ball query via grid (wave per query)
__global__ __launch_bounds__(256) void ballq_kernel(
    const float* __restrict__ xyz,
    const int* __restrict__ cellStart,
    const int* __restrict__ sortedId,
    const float* __restrict__ sortedXyz,
    int* __restrict__ idx)
{
    __shared__ int hitbuf[4][128];
    int t = threadIdx.x;
    int w = t >> 6, lane = t & 63;
    int g = blockIdx.x * 4 + w;
    int b = g >> 11, s = g & 2047;
    const float* qp = xyz + ((size_t)(b * N_) + s) * 3;
    float qx = qp[0], qy = qp[1], qz = qp[2];
    const float r2 = 0.01f;   // f32(0.1(f64)^2) == 0.01f exactly
    unsigned long long lmask = (1ull << lane) - 1ull;

    int cx = (int)(qx * 9.999f), cy = (int)(qy * 9.999f), cz = (int)(qz * 9.999f);
    int xlo = max(cx - 1, 0), xhi = min(cx + 1, GD - 1);
    int ylo = max(cy - 1, 0), yhi = min(cy + 1, GD - 1);
    int zlo = max(cz - 1, 0), zhi = min(cz + 1, GD - 1);
    int nx = xhi - xlo + 1, ny = yhi - ylo + 1;
    int nruns = nx * ny;                 // <= 9 contiguous z-runs

    const int* cs = cellStart + b * (NCP + 1);
    int start = 0, len = 0;
    if (lane < nruns) {
        int xi = xlo + lane / ny, yi = ylo + lane % ny;
        int cbase = (xi * GD + yi) * GD;
        start = cs[cbase + zlo];
        len = cs[cbase + zhi + 1] - start;
    }
    // wave exclusive scan of len
    int v = len;
    for (int d = 1; d < 64; d <<= 1) {
        int o = __shfl_up(v, d);
        if (lane >= d) v += o;
    }
    int T = __shfl(v, 63);
    int excl = v - len;
    // broadcast run tables to all lanes via shfl (values live in lanes 0..8)
    int ro[9], rs[9];
#pragma unroll
    for (int rr = 0; rr < 9; ++rr) {
        int oo = __shfl(excl, rr);
        int ss = __shfl(start, rr);
        bool live = rr < nruns;
        ro[rr] = live ? oo : 0x7fffffff;
        rs[rr] = live ? (ss - oo) : 0;
    }

    int cnt = 0;
    for (int k0 = 0; k0 < T; k0 += 64) {
        int pos = k0 + lane;
        bool valid = pos < T;
        int basev = rs[0];
#pragma unroll
        for (int rr = 1; rr < 9; ++rr)
            basev = (ro[rr] <= pos) ? rs[rr] : basev;
        float px = 1.e30f, py = 1.e30f, pz = 1.e30f;
        int pid = 0;
        if (valid) {
            int src = basev + pos;
            const float* pp = sortedXyz + ((size_t)(b * N_) + src) * 3;
            px = pp[0]; py = pp[1]; pz = pp[2];
            pid = sortedId[b * N_ + src];
        }
        // bit-exact reference arithmetic: no FMA, (dx^2+dy^2)+dz^2
        float dx = __fsub_rn(px, qx);
        float dy = __fsub_rn(py, qy);
        float dz = __fsub_rn(pz, qz);
        float d2 = __fadd_rn(__fadd_rn(__fmul_rn(dx, dx), __fmul_rn(dy, dy)),
                             __fmul_rn(dz, dz));
        bool pred = valid && (d2 < r2);
        unsigned long long m = __ballot(pred);
        if (pred) {
            int p = cnt + __builtin_popcountll(m & lmask);
            if (p < 128) hitbuf[w][p] = pid;
        }
        cnt += __builtin_popcountll(m);
    }

    // 128-wide in-register bitonic sort ascending (INF pad); idx0=lane, idx1=64+lane
    const int INF = 0x7fffffff;
    int v0 = (lane < cnt && lane < 128) ? hitbuf[w][lane] : INF;
    int v1 = (lane + 64 < cnt) ? hitbuf[w][lane + 64] : INF;
#pragma unroll
    for (int k = 2; k <= 128; k <<= 1) {
#pragma unroll
        for (int j = 64; j >= 1; j >>= 1) {
            if (j > (k >> 1)) continue;
            if (j == 64) {
                int lo = min(v0, v1), hi = max(v0, v1);
                v0 = lo; v1 = hi;     // k==128: ascending everywhere
            } else {
                int p0 = __shfl_xor(v0, j), p1 = __shfl_xor(v1, j);
                bool lower = (lane & j) == 0;
                bool asc0 = (lane & k) == 0;
                bool asc1 = ((lane + 64) & k) == 0;
                v0 = (lower == asc0) ? min(v0, p0) : max(v0, p0);
                v1 = (lower == asc1) ? min(v1, p1) : max(v1, p1);
            }
        }
    }
    int first = __shfl(v0, 0);          // smallest in-ball index (self always hits)
    if (lane < NS) {
        int val = (lane < cnt) ? v0 : first;
        idx[(size_t)g * NS + lane] = val;
    }
}

// ---------------------------------------------------------------- fused gather + MLP + maxpool (MFMA)
// Wave per group, 4 groups/block, ZERO LDS.
// L1: 16x16x32 (A[row=l&15][k=8*(l>>4)+j], B[k][col=l&15], D[row=(l>>4)*4+r][col=l&15]).
// L2: 16x16x16 (k-chunk = 4*(l>>4)+i) -- B operand is the lane's OWN relu'd L1 acc.
__global__ __launch_bounds__(256) void mlp_mfma_kernel(
    const float* __restrict__ xyz,
    const unsigned short* __restrict__ fT_hi, const unsigned short* __restrict__ fT_lo,
    const unsigned short* __restrict__ W1x_hi, const unsigned short* __restrict__ W1x_lo,
    const float* __restrict__ b1,
    const unsigned short* __restrict__ W2x_hi, const unsigned short* __restrict__ W2x_lo,
    const float* __restrict__ b2,
    const int* __restrict__ idx,
    float* __restrict__ Ytmp)          // (B,S,128) f32
{
    int t = threadIdx.x;
    int w = t >> 6, lane = t & 63;
    int g = blockIdx.x * 4 + w;
    int b = g >> 11, s = g & 2047;
    int cl = lane & 15, kq = lane >> 4;

    int i0 = idx[(size_t)g * NS + cl];
    int i1 = idx[(size_t)g * NS + 16 + cl];

    // ---- B fragments: features, hi/lo, 2 k-tiles x 2 n-tiles
    bf16x8 bh[2][2], bl[2][2];
#pragma unroll
    for (int nt = 0; nt < 2; ++nt) {
        int i = nt ? i1 : i0;
        size_t rowoff = ((size_t)(b * N_ + i)) * C_ + kq * 8;
#pragma unroll
        for (int kt = 0; kt < 2; ++kt) {
            bh[nt][kt] = *reinterpret_cast<const bf16x8*>(fT_hi + rowoff + kt * 32);
            bl[nt][kt] = *reinterpret_cast<const bf16x8*>(fT_lo + rowoff + kt * 32);
        }
    }
    // ---- rel k-tile B fragment (k 64..66 live; only kq==0 lanes carry data)
    const float* qp = xyz + ((size_t)(b * N_) + s) * 3;
    float qx = qp[0], qy = qp[1], qz = qp[2];
    bf16x8 brel[2];
#pragma unroll
    for (int nt = 0; nt < 2; ++nt) {
        int i = nt ? i1 : i0;
        bf16x8 vv = (bf16x8)(short)0;
        if (kq == 0) {
            const float* p = xyz + ((size_t)(b * N_) + i) * 3;
            vv[0] = (short)f2bf(__fsub_rn(p[0], qx));
            vv[1] = (short)f2bf(__fsub_rn(p[1], qy));
            vv[2] = (short)f2bf(__fsub_rn(p[2], qz));
        }
        brel[nt] = vv;
    }

    // ---- Layer 1: H(64x32) = W1(64x96) * X(96x32)
    f32x4 acc[4][2];
#pragma unroll
    for (int mt = 0; mt < 4; ++mt) {
        f32x4 bias = *reinterpret_cast<const f32x4*>(b1 + mt * 16 + kq * 4);
        acc[mt][0] = bias;
        acc[mt][1] = bias;
    }
#pragma unroll
    for (int mt = 0; mt < 4; ++mt) {
        bf16x8 ah0 = *reinterpret_cast<const bf16x8*>(W1x_hi + (mt * 3 + 0) * 512 + lane * 8);
        bf16x8 ah1 = *reinterpret_cast<const bf16x8*>(W1x_hi + (mt * 3 + 1) * 512 + lane * 8);
        bf16x8 ah2 = *reinterpret_cast<const bf16x8*>(W1x_hi + (mt * 3 + 2) * 512 + lane * 8);
        bf16x8 al0 = *reinterpret_cast<const bf16x8*>(W1x_lo + (mt * 3 + 0) * 512 + lane * 8);
        bf16x8 al1 = *reinterpret_cast<const bf16x8*>(W1x_lo + (mt * 3 + 1) * 512 + lane * 8);
#pragma unroll
        for (int nt = 0; nt < 2; ++nt) {
            f32x4 a = acc[mt][nt];
            a = MFMA32(ah0, bh[nt][0], a, 0, 0, 0);
            a = MFMA32(ah0, bl[nt][0], a, 0, 0, 0);
            a = MFMA32(al0, bh[nt][0], a, 0, 0, 0);
            a = MFMA32(ah1, bh[nt][1], a, 0, 0, 0);
            a = MFMA32(ah1, bl[nt][1], a, 0, 0, 0);
            a = MFMA32(al1, bh[nt][1], a, 0, 0, 0);
            a = MFMA32(ah2, brel[nt], a, 0, 0, 0);
            acc[mt][nt] = a;
        }
    }

    // ---- relu + hi/lo split IN-LANE -> L2 B fragments (p2h/p2l[kt2][nt])
    bf16x4 p2h[4][2], p2l[4][2];
#pragma unroll
    for (int kt2 = 0; kt2 < 4; ++kt2)
#pragma unroll
        for (int nt = 0; nt < 2; ++nt) {
            f32x4 h = acc[kt2][nt];
            bf16x4 hh, hl;
#pragma unroll
            for (int i = 0; i < 4; ++i) {
                float hr = fmaxf(h[i], 0.f);
                unsigned short hb = f2bf(hr);
                hh[i] = (short)hb;
                hl[i] = (short)f2bf(hr - bf2f(hb));
            }
            p2h[kt2][nt] = hh;
            p2l[kt2][nt] = hl;
        }

    // ---- Layer 2 in two mt-halves (keeps acc2 at 32 regs)
#pragma unroll
    for (int hm = 0; hm < 2; ++hm) {
        f32x4 acc2[4][2];
#pragma unroll
        for (int mt4 = 0; mt4 < 4; ++mt4) {
            f32x4 bias = *reinterpret_cast<const f32x4*>(b2 + (hm * 4 + mt4) * 16 + kq * 4);
            acc2[mt4][0] = bias;
            acc2[mt4][1] = bias;
        }
#pragma unroll
        for (int mt4 = 0; mt4 < 4; ++mt4) {
            int mt = hm * 4 + mt4;
#pragma unroll
            for (int kt2p = 0; kt2p < 2; ++kt2p) {
                bf16x8 ah = *reinterpret_cast<const bf16x8*>(W2x_hi + (mt * 2 + kt2p) * 512 + lane * 8);
                bf16x8 al = *reinterpret_cast<const bf16x8*>(W2x_lo + (mt * 2 + kt2p) * 512 + lane * 8);
                bf16x4 ah_a = __builtin_shufflevector(ah, ah, 0, 1, 2, 3);
                bf16x4 ah_b = __builtin_shufflevector(ah, ah, 4, 5, 6, 7);
                bf16x4 al_a = __builtin_shufflevector(al, al, 0, 1, 2, 3);
                bf16x4 al_b = __builtin_shufflevector(al, al, 4, 5, 6, 7);
#pragma unroll
                for (int nt = 0; nt < 2; ++nt) {
                    f32x4 a = acc2[mt4][nt];
                    a = MFMA16(ah_a, p2h[kt2p * 2][nt], a, 0, 0, 0);
                    a = MFMA16(ah_a, p2l[kt2p * 2][nt], a, 0, 0, 0);
                    a = MFMA16(al_a, p2h[kt2p * 2][nt], a, 0, 0, 0);
                    a = MFMA16(ah_b, p2h[kt2p * 2 + 1][nt], a, 0, 0, 0);
                    a = MFMA16(ah_b, p2l[kt2p * 2 + 1][nt], a, 0, 0, 0);
                    a = MFMA16(al_b, p2h[kt2p * 2 + 1][nt], a, 0, 0, 0);
                    acc2[mt4][nt] = a;
                }
            }
        }
        // ---- relu + maxpool over 32 samples + store
#pragma unroll
        for (int mt4 = 0; mt4 < 4; ++mt4) {
            f32x4 m;
#pragma unroll
            for (int r = 0; r < 4; ++r)
                m[r] = fmaxf(fmaxf(acc2[mt4][0][r], 0.f), fmaxf(acc2[mt4][1][r], 0.f));
#pragma unroll
            for (int mask = 1; mask <= 8; mask <<= 1)
#pragma unroll
                for (int r = 0; r < 4; ++r)
                    m[r] = fmaxf(m[r], __shfl_xor(m[r], mask));
            if (cl == 0)
                *reinterpret_cast<f32x4*>(Ytmp + (size_t)g * H2_ + (hm * 4 + mt4) * 16 + kq * 4) = m;
        }
    }
}

// ---------------------------------------------------------------- Ytmp (B,S,128) -> out (B,128,S)
__global__ __launch_bounds__(256) void ytrans_kernel(
    const float* __restrict__ Y, float* __restrict__ out)
{
    __shared__ float tile[64][65];
    int blk = blockIdx.x;
    int b = blk >> 6, r = blk & 63;
    int st = r >> 1, ot = r & 1;
    int s0 = st * 64, o0 = ot * 64;
    int j = threadIdx.x & 63, i4 = threadIdx.x >> 6;
#pragma unroll
    for (int k = 0; k < 16; ++k) {
        int i = i4 * 16 + k;
        tile[i][j] = Y[((size_t)(b * NPOINT + s0 + i)) * H2_ + o0 + j];
    }
    __syncthreads();
#pragma unroll
    for (int k = 0; k < 16; ++k) {
        int i = i4 * 16 + k;
        out[NXYZ + ((size_t)(b * H2_ + o0 + i)) * NPOINT + s0 + j] = tile[j][i];
    }
}

// ---------------------------------------------------------------- launcher
extern "C" void kernel_launch(void* const* d_in, const int* in_sizes, int n_in,
                              void* d_out, int out_size, void* d_ws, size_t ws_size,
                              hipStream_t stream)
{
    const float* xyz  = (const float*)d_in[0];
    const float* feat = (const float*)d_in[1];
    const float* W1   = (const float*)d_in[2];
    const float* b1   = (const float*)d_in[3];
    const float* W2   = (const float*)d_in[4];
    const float* b2   = (const float*)d_in[5];
    float* out = (float*)d_out;

    char* ws = (char*)d_ws;
    size_t off = 0;
    int* idxbuf = (int*)(ws + off);                        off += (size_t)NGROUP * NS * 4;     // 2 MiB
    unsigned short* W1x_hi = (unsigned short*)(ws + off);  off += 6144 * 2;
    unsigned short* W1x_lo = (unsigned short*)(ws + off);  off += 6144 * 2;
    unsigned short* W2x_hi = (unsigned short*)(ws + off);  off += 8192 * 2;
    unsigned short* W2x_lo = (unsigned short*)(ws + off);  off += 8192 * 2;
    off = (off + 255) & ~(size_t)255;
    int* cellStart = (int*)(ws + off);                     off += (size_t)B_ * (NCP + 1) * 4;
    int* sortedId = (int*)(ws + off);                      off += (size_t)B_ * N_ * 4;
    float* sortedXyz = (float*)(ws + off);                 off += (size_t)B_ * N_ * 3 * 4;
    off = (off + 255) & ~(size_t)255;
    unsigned short* fT_hi = (unsigned short*)(ws + off);   off += (size_t)B_ * N_ * C_ * 2;    // 8 MiB
    unsigned short* fT_lo = (unsigned short*)(ws + off);   off += (size_t)B_ * N_ * C_ * 2;    // 8 MiB
    float* Ytmp = (float*)(ws + off);                      off += (size_t)NGROUP * H2_ * 4;    // 8 MiB

    copy_newxyz_kernel<<<(NXYZ + 255) / 256, 256, 0, stream>>>(xyz, out);
    prep_kernel<<<32, 256, 0, stream>>>(W1, W2, W1x_hi, W1x_lo, W2x_hi, W2x_lo);
    ftrans_kernel<<<B_ * (N_ / 64), 256, 0, stream>>>(feat, fT_hi, fT_lo);
    gridbuild_kernel<<<B_, 256, 0, stream>>>(xyz, cellStart, sortedId, sortedXyz);
    ballq_kernel<<<NGROUP / 4, 256, 0, stream>>>(xyz, cellStart, sortedId, sortedXyz, idxbuf);
    mlp_mfma_kernel<<<NGROUP / 4, 256, 0, stream>>>(
        xyz, fT_hi, fT_lo, W1x_hi, W1x_lo, b1, W2x_hi, W2x_lo, b2, idxbuf, Ytmp);
    ytrans_kernel<<<B_ * 64, 256, 0, stream>>>(Ytmp, out);
}

// Round 5
// 178.266 us; speedup vs baseline: 2.0993x; 1.0732x over previous
//
#include <hip/hip_runtime.h>
#include <hip/hip_bf16.h>

#define B_      8
#define N_      8192
#define C_      64
#define H1_     64
#define H2_     128
#define NS      32
#define NPOINT  2048
#define NGROUP  (B_ * NPOINT)          // 16384
#define NXYZ    (B_ * NPOINT * 3)      // 49152
#define GD      10
#define NCP     1024                   // padded cell count (1000 used)

typedef short bf16x8 __attribute__((ext_vector_type(8)));
typedef short bf16x4 __attribute__((ext_vector_type(4)));
typedef float f32x4  __attribute__((ext_vector_type(4)));

#define MFMA32 __builtin_amdgcn_mfma_f32_16x16x32_bf16
#define MFMA16 __builtin_amdgcn_mfma_f32_16x16x16bf16_1k

__device__ inline unsigned short f2bf(float f) {
    unsigned u = __builtin_bit_cast(unsigned, f);
    return (unsigned short)((u + 0x7FFF + ((u >> 16) & 1)) >> 16);
}
__device__ inline float bf2f(unsigned short h) {
    unsigned u = ((unsigned)h) << 16;
    return __builtin_bit_cast(float, u);
}

// ================================================================ K1: all prep
// blocks [0,1024): ftrans  (B,C,N) f32 -> (B,N,C) bf16 hi/lo
// blocks [1024,1032): gridbuild (counting sort by cell, 1 block per batch)
// blocks [1032,1056): new_xyz copy (float4)
// blocks [1056,1088): weight prep (hi/lo, MFMA-permuted)
__global__ __launch_bounds__(256) void prep_all_kernel(
    const float* __restrict__ xyz, const float* __restrict__ feat,
    const float* __restrict__ W1, const float* __restrict__ W2,
    unsigned short* __restrict__ fT_hi, unsigned short* __restrict__ fT_lo,
    int* __restrict__ cellStart, int* __restrict__ sortedId,
    float* __restrict__ sortedXyz,
    unsigned short* __restrict__ W1x_hi, unsigned short* __restrict__ W1x_lo,
    unsigned short* __restrict__ W2x_hi, unsigned short* __restrict__ W2x_lo,
    float* __restrict__ out)
{
    __shared__ char smem[64 * 65 * 4];       // 16640 B, unioned across branches
    int blk = blockIdx.x, t = threadIdx.x;

    if (blk < 1024) {
        // ---------------- ftrans
        float (*tile)[65] = reinterpret_cast<float(*)[65]>(smem);
        int b = blk >> 7, nt = blk & 127;
        int n0 = nt * 64;
        int tx = t & 63, ty = t >> 6;
#pragma unroll
        for (int k = 0; k < 16; ++k) {
            int c = ty * 16 + k;
            tile[c][tx] = feat[((size_t)b * C_ + c) * N_ + n0 + tx];
        }
        __syncthreads();
#pragma unroll
        for (int k = 0; k < 16; ++k) {
            int n = ty * 16 + k;
            float v = tile[tx][n];
            unsigned short h = f2bf(v);
            size_t dst = ((size_t)(b * N_ + n0 + n)) * C_ + tx;
            fT_hi[dst] = h;
            fT_lo[dst] = f2bf(v - bf2f(h));
        }
    } else if (blk < 1032) {
        // ---------------- gridbuild: cell = (int)(x*9.999f), |dcell|<=1 for d<0.1
        int* hist = reinterpret_cast<int*>(smem);
        int* wsum = hist + NCP;
        int b = blk - 1024;
        for (int i = t; i < NCP; i += 256) hist[i] = 0;
        __syncthreads();
        const float* base = xyz + (size_t)b * N_ * 3;
        for (int k = 0; k < N_ / 256; ++k) {
            int i = k * 256 + t;
            float x = base[i * 3], y = base[i * 3 + 1], z = base[i * 3 + 2];
            int c = (((int)(x * 9.999f)) * GD + (int)(y * 9.999f)) * GD + (int)(z * 9.999f);
            atomicAdd(&hist[c], 1);
        }
        __syncthreads();
        int h0 = hist[t * 4], h1 = hist[t * 4 + 1], h2 = hist[t * 4 + 2], h3 = hist[t * 4 + 3];
        int s = h0 + h1 + h2 + h3;
        int lane = t & 63, w = t >> 6;
        int v = s;
        for (int d = 1; d < 64; d <<= 1) {
            int o = __shfl_up(v, d);
            if (lane >= d) v += o;
        }
        if (lane == 63) wsum[w] = v;
        __syncthreads();
        int wofs = 0;
        for (int i = 0; i < 4; ++i) wofs += (i < w) ? wsum[i] : 0;
        int excl = wofs + v - s;
        int* cs = cellStart + b * (NCP + 1);
        cs[t * 4]     = excl;
        cs[t * 4 + 1] = excl + h0;
        cs[t * 4 + 2] = excl + h0 + h1;
        cs[t * 4 + 3] = excl + h0 + h1 + h2;
        if (t == 255) cs[NCP] = excl + s;
        __syncthreads();
        hist[t * 4] = excl; hist[t * 4 + 1] = excl + h0;
        hist[t * 4 + 2] = excl + h0 + h1; hist[t * 4 + 3] = excl + h0 + h1 + h2;
        __syncthreads();
        for (int k = 0; k < N_ / 256; ++k) {
            int i = k * 256 + t;
            float x = base[i * 3], y = base[i * 3 + 1], z = base[i * 3 + 2];
            int c = (((int)(x * 9.999f)) * GD + (int)(y * 9.999f)) * GD + (int)(z * 9.999f);
            int pos = atomicAdd(&hist[c], 1);
            sortedId[b * N_ + pos] = i;
            float* d = sortedXyz + ((size_t)(b * N_) + pos) * 3;
            d[0] = x; d[1] = y; d[2] = z;
        }
    } else if (blk < 1056) {
        // ---------------- new_xyz copy (float4 granularity)
        const float4* src = reinterpret_cast<const float4*>(xyz);
        float4* dst = reinterpret_cast<float4*>(out);
#pragma unroll
        for (int k = 0; k < 2; ++k) {
            int i4 = (blk - 1032) * 512 + k * 256 + t;      // < 12288
            int b = i4 / 1536, r = i4 - b * 1536;
            dst[i4] = src[b * 6144 + r];
        }
    } else {
        // ---------------- weight prep
        int tg = (blk - 1056) * 256 + t;
        if (tg < 6144) {
            int j = tg & 7, cl = (tg >> 3) & 15, kq = (tg >> 7) & 3, t2 = tg >> 9;
            int kt = t2 % 3, mt = t2 / 3;
            int row = mt * 16 + cl, k = kt * 32 + kq * 8 + j;
            float wv = 0.f;
            if (k < 64) wv = W1[row * 67 + 3 + k];
            else if (k < 67) wv = W1[row * 67 + (k - 64)];
            unsigned short h = f2bf(wv);
            W1x_hi[tg] = h; W1x_lo[tg] = f2bf(wv - bf2f(h));
        }
        if (tg < 8192) {
            int i = tg & 3, half = (tg >> 2) & 1, cl = (tg >> 3) & 15;
            int kq = (tg >> 7) & 3, kt2p = (tg >> 9) & 1, mt = tg >> 10;
            int row = mt * 16 + cl, k = kt2p * 32 + half * 16 + kq * 4 + i;
            float wv = W2[row * 64 + k];
            unsigned short h = f2bf(wv);
            W2x_hi[tg] = h; W2x_lo[tg] = f2bf(wv - bf2f(h));
        }
    }
}

// ================================================================ K2: fused ballq + MLP + maxpool + store
// Wave per group, 4 groups/block (4 consecutive s, same b).
// ballq: grid walk + ballot compact + 128-wide in-register bitonic sort (round-4 verified).
// MLP: L1 16x16x32 bf16 hi/lo split; L2 16x16x16 with B = lane's own relu'd L1 acc (zero LDS).
// Store: maxpool -> LDS ystage -> block-cooperative float4 stores in (B,128,S) layout.
__global__ __launch_bounds__(256) void fused_kernel(
    const float* __restrict__ xyz,
    const int* __restrict__ cellStart,
    const int* __restrict__ sortedId,
    const float* __restrict__ sortedXyz,
    const unsigned short* __restrict__ fT_hi, const unsigned short* __restrict__ fT_lo,
    const unsigned short* __restrict__ W1x_hi, const unsigned short* __restrict__ W1x_lo,
    const float* __restrict__ b1,
    const unsigned short* __restrict__ W2x_hi, const unsigned short* __restrict__ W2x_lo,
    const float* __restrict__ b2,
    float* __restrict__ out)
{
    __shared__ int shbuf[4][128];            // hitbuf (per-wave), then ystage
    int t = threadIdx.x;
    int w = t >> 6, lane = t & 63;
    int g = blockIdx.x * 4 + w;
    int b = g >> 11, s = g & 2047;

    // ---------------- ball query ----------------
    const float* qp = xyz + ((size_t)(b * N_) + s) * 3;
    float qx = qp[0], qy = qp[1], qz = qp[2];
    const float r2 = 0.01f;   // f32(0.1(f64)^2) == 0.01f exactly
    unsigned long long lmask = (1ull << lane) - 1ull;

    int cx = (int)(qx * 9.999f), cy = (int)(qy * 9.999f), cz = (int)(qz * 9.999f);
    int xlo = max(cx - 1, 0), xhi = min(cx + 1, GD - 1);
    int ylo = max(cy - 1, 0), yhi = min(cy + 1, GD - 1);
    int zlo = max(cz - 1, 0), zhi = min(cz + 1, GD - 1);
    int nx = xhi - xlo + 1, ny = yhi - ylo + 1;
    int nruns = nx * ny;                     // <= 9 contiguous z-runs

    const int* cs = cellStart + b * (NCP + 1);
    int start = 0, len = 0;
    if (lane < nruns) {
        int xi = xlo + lane / ny, yi = ylo + lane % ny;
        int cbase = (xi * GD + yi) * GD;
        start = cs[cbase + zlo];
        len = cs[cbase + zhi + 1] - start;
    }
    int v = len;
    for (int d = 1; d < 64; d <<= 1) {
        int o = __shfl_up(v, d);
        if (lane >= d) v += o;
    }
    int T = __shfl(v, 63);
    int excl = v - len;
    int ro[9], rs[9];
#pragma unroll
    for (int rr = 0; rr < 9; ++rr) {
        int oo = __shfl(excl, rr);
        int ss = __shfl(start, rr);
        bool live = rr < nruns;
        ro[rr] = live ? oo : 0x7fffffff;
        rs[rr] = live ? (ss - oo) : 0;
    }

    int cnt = 0;
    for (int k0 = 0; k0 < T; k0 += 64) {
        int pos = k0 + lane;
        bool valid = pos < T;
        int basev = rs[0];
#pragma unroll
        for (int rr = 1; rr < 9; ++rr)
            basev = (ro[rr] <= pos) ? rs[rr] : basev;
        float px = 1.e30f, py = 1.e30f, pz = 1.e30f;
        int pid = 0;
        if (valid) {
            int src = basev + pos;
            const float* pp = sortedXyz + ((size_t)(b * N_) + src) * 3;
            px = pp[0]; py = pp[1]; pz = pp[2];
            pid = sortedId[b * N_ + src];
        }
        // bit-exact reference arithmetic: no FMA, (dx^2+dy^2)+dz^2
        float dx = __fsub_rn(px, qx);
        float dy = __fsub_rn(py, qy);
        float dz = __fsub_rn(pz, qz);
        float d2 = __fadd_rn(__fadd_rn(__fmul_rn(dx, dx), __fmul_rn(dy, dy)),
                             __fmul_rn(dz, dz));
        bool pred = valid && (d2 < r2);
        unsigned long long m = __ballot(pred);
        if (pred) {
            int p = cnt + __builtin_popcountll(m & lmask);
            if (p < 128) shbuf[w][p] = pid;
        }
        cnt += __builtin_popcountll(m);
    }

    // 128-wide in-register bitonic sort ascending (INF pad)
    const int INF = 0x7fffffff;
    int v0 = (lane < cnt && lane < 128) ? shbuf[w][lane] : INF;
    int v1 = (lane + 64 < cnt) ? shbuf[w][lane + 64] : INF;
#pragma unroll
    for (int k = 2; k <= 128; k <<= 1) {
#pragma unroll
        for (int j = 64; j >= 1; j >>= 1) {
            if (j > (k >> 1)) continue;
            if (j == 64) {
                int lo = min(v0, v1), hi = max(v0, v1);
                v0 = lo; v1 = hi;
            } else {
                int p0 = __shfl_xor(v0, j), p1 = __shfl_xor(v1, j);
                bool lower = (lane & j) == 0;
                bool asc0 = (lane & k) == 0;
                bool asc1 = ((lane + 64) & k) == 0;
                v0 = (lower == asc0) ? min(v0, p0) : max(v0, p0);
                v1 = (lower == asc1) ? min(v1, p1) : max(v1, p1);
            }
        }
    }
    int first = __shfl(v0, 0);               // self always in ball -> cnt>=1
    int cl = lane & 15, kq = lane >> 4;
    int sv0 = __shfl(v0, cl);
    int sv1 = __shfl(v0, cl + 16);
    int i0 = (cl < cnt) ? sv0 : first;
    int i1 = (cl + 16 < cnt) ? sv1 : first;

    // ---------------- MLP ----------------
    bf16x8 bh[2][2], bl[2][2];
#pragma unroll
    for (int nt = 0; nt < 2; ++nt) {
        int i = nt ? i1 : i0;
        size_t rowoff = ((size_t)(b * N_ + i)) * C_ + kq * 8;
#pragma unroll
        for (int kt = 0; kt < 2; ++kt) {
            bh[nt][kt] = *reinterpret_cast<const bf16x8*>(fT_hi + rowoff + kt * 32);
            bl[nt][kt] = *reinterpret_cast<const bf16x8*>(fT_lo + rowoff + kt * 32);
        }
    }
    bf16x8 brel[2];
#pragma unroll
    for (int nt = 0; nt < 2; ++nt) {
        int i = nt ? i1 : i0;
        bf16x8 vv = (bf16x8)(short)0;
        if (kq == 0) {
            const float* p = xyz + ((size_t)(b * N_) + i) * 3;
            vv[0] = (short)f2bf(__fsub_rn(p[0], qx));
            vv[1] = (short)f2bf(__fsub_rn(p[1], qy));
            vv[2] = (short)f2bf(__fsub_rn(p[2], qz));
        }
        brel[nt] = vv;
    }

    // Layer 1: H(64x32) = W1(64x96) * X(96x32)
    f32x4 acc[4][2];
#pragma unroll
    for (int mt = 0; mt < 4; ++mt) {
        f32x4 bias = *reinterpret_cast<const f32x4*>(b1 + mt * 16 + kq * 4);
        acc[mt][0] = bias;
        acc[mt][1] = bias;
    }
#pragma unroll
    for (int mt = 0; mt < 4; ++mt) {
        bf16x8 ah0 = *reinterpret_cast<const bf16x8*>(W1x_hi + (mt * 3 + 0) * 512 + lane * 8);
        bf16x8 ah1 = *reinterpret_cast<const bf16x8*>(W1x_hi + (mt * 3 + 1) * 512 + lane * 8);
        bf16x8 ah2 = *reinterpret_cast<const bf16x8*>(W1x_hi + (mt * 3 + 2) * 512 + lane * 8);
        bf16x8 al0 = *reinterpret_cast<const bf16x8*>(W1x_lo + (mt * 3 + 0) * 512 + lane * 8);
        bf16x8 al1 = *reinterpret_cast<const bf16x8*>(W1x_lo + (mt * 3 + 1) * 512 + lane * 8);
#pragma unroll
        for (int nt = 0; nt < 2; ++nt) {
            f32x4 a = acc[mt][nt];
            a = MFMA32(ah0, bh[nt][0], a, 0, 0, 0);
            a = MFMA32(ah0, bl[nt][0], a, 0, 0, 0);
            a = MFMA32(al0, bh[nt][0], a, 0, 0, 0);
            a = MFMA32(ah1, bh[nt][1], a, 0, 0, 0);
            a = MFMA32(ah1, bl[nt][1], a, 0, 0, 0);
            a = MFMA32(al1, bh[nt][1], a, 0, 0, 0);
            a = MFMA32(ah2, brel[nt], a, 0, 0, 0);
            acc[mt][nt] = a;
        }
    }

    // relu + hi/lo split IN-LANE -> L2 B fragments
    bf16x4 p2h[4][2], p2l[4][2];
#pragma unroll
    for (int kt2 = 0; kt2 < 4; ++kt2)
#pragma unroll
        for (int nt = 0; nt < 2; ++nt) {
            f32x4 h = acc[kt2][nt];
            bf16x4 hh, hl;
#pragma unroll
            for (int i = 0; i < 4; ++i) {
                float hr = fmaxf(h[i], 0.f);
                unsigned short hb = f2bf(hr);
                hh[i] = (short)hb;
                hl[i] = (short)f2bf(hr - bf2f(hb));
            }
            p2h[kt2][nt] = hh;
            p2l[kt2][nt] = hl;
        }

    // Layer 2 in two mt-halves; maxpool into LDS ystage
    float* ys = reinterpret_cast<float*>(&shbuf[0][0]);
#pragma unroll
    for (int hm = 0; hm < 2; ++hm) {
        f32x4 acc2[4][2];
#pragma unroll
        for (int mt4 = 0; mt4 < 4; ++mt4) {
            f32x4 bias = *reinterpret_cast<const f32x4*>(b2 + (hm * 4 + mt4) * 16 + kq * 4);
            acc2[mt4][0] = bias;
            acc2[mt4][1] = bias;
        }
#pragma unroll
        for (int mt4 = 0; mt4 < 4; ++mt4) {
            int mt = hm * 4 + mt4;
#pragma unroll
            for (int kt2p = 0; kt2p < 2; ++kt2p) {
                bf16x8 ah = *reinterpret_cast<const bf16x8*>(W2x_hi + (mt * 2 + kt2p) * 512 + lane * 8);
                bf16x8 al = *reinterpret_cast<const bf16x8*>(W2x_lo + (mt * 2 + kt2p) * 512 + lane * 8);
                bf16x4 ah_a = __builtin_shufflevector(ah, ah, 0, 1, 2, 3);
                bf16x4 ah_b = __builtin_shufflevector(ah, ah, 4, 5, 6, 7);
                bf16x4 al_a = __builtin_shufflevector(al, al, 0, 1, 2, 3);
                bf16x4 al_b = __builtin_shufflevector(al, al, 4, 5, 6, 7);
#pragma unroll
                for (int nt = 0; nt < 2; ++nt) {
                    f32x4 a = acc2[mt4][nt];
                    a = MFMA16(ah_a, p2h[kt2p * 2][nt], a, 0, 0, 0);
                    a = MFMA16(ah_a, p2l[kt2p * 2][nt], a, 0, 0, 0);
                    a = MFMA16(al_a, p2h[kt2p * 2][nt], a, 0, 0, 0);
                    a = MFMA16(ah_b, p2h[kt2p * 2 + 1][nt], a, 0, 0, 0);
                    a = MFMA16(ah_b, p2l[kt2p * 2 + 1][nt], a, 0, 0, 0);
                    a = MFMA16(al_b, p2h[kt2p * 2 + 1][nt], a, 0, 0, 0);
                    acc2[mt4][nt] = a;
                }
            }
        }
#pragma unroll
        for (int mt4 = 0; mt4 < 4; ++mt4) {
            f32x4 m;
#pragma unroll
            for (int r = 0; r < 4; ++r)
                m[r] = fmaxf(fmaxf(acc2[mt4][0][r], 0.f), fmaxf(acc2[mt4][1][r], 0.f));
#pragma unroll
            for (int mask = 1; mask <= 8; mask <<= 1)
#pragma unroll
                for (int r = 0; r < 4; ++r)
                    m[r] = fmaxf(m[r], __shfl_xor(m[r], mask));
            if (cl == 0)
                *reinterpret_cast<f32x4*>(ys + w * 128 + (hm * 4 + mt4) * 16 + kq * 4) = m;
        }
    }

    // ---------------- cooperative transposed store ----------------
    __syncthreads();
    if (t < 128) {
        int o = t;
        int bb = blockIdx.x >> 9;
        int s0 = (blockIdx.x & 511) * 4;
        float4 vv = { ys[0 * 128 + o], ys[1 * 128 + o], ys[2 * 128 + o], ys[3 * 128 + o] };
        *reinterpret_cast<float4*>(out + NXYZ + ((size_t)(bb * H2_ + o)) * NPOINT + s0) = vv;
    }
}

// ================================================================ launcher
extern "C" void kernel_launch(void* const* d_in, const int* in_sizes, int n_in,
                              void* d_out, int out_size, void* d_ws, size_t ws_size,
                              hipStream_t stream)
{
    const float* xyz  = (const float*)d_in[0];
    const float* feat = (const float*)d_in[1];
    const float* W1   = (const float*)d_in[2];
    const float* b1   = (const float*)d_in[3];
    const float* W2   = (const float*)d_in[4];
    const float* b2   = (const float*)d_in[5];
    float* out = (float*)d_out;

    char* ws = (char*)d_ws;
    size_t off = 0;
    unsigned short* W1x_hi = (unsigned short*)(ws + off);  off += 6144 * 2;
    unsigned short* W1x_lo = (unsigned short*)(ws + off);  off += 6144 * 2;
    unsigned short* W2x_hi = (unsigned short*)(ws + off);  off += 8192 * 2;
    unsigned short* W2x_lo = (unsigned short*)(ws + off);  off += 8192 * 2;
    off = (off + 255) & ~(size_t)255;
    int* cellStart = (int*)(ws + off);                     off += (size_t)B_ * (NCP + 1) * 4;
    int* sortedId = (int*)(ws + off);                      off += (size_t)B_ * N_ * 4;
    float* sortedXyz = (float*)(ws + off);                 off += (size_t)B_ * N_ * 3 * 4;
    off = (off + 255) & ~(size_t)255;
    unsigned short* fT_hi = (unsigned short*)(ws + off);   off += (size_t)B_ * N_ * C_ * 2;    // 8 MiB
    unsigned short* fT_lo = (unsigned short*)(ws + off);   off += (size_t)B_ * N_ * C_ * 2;    // 8 MiB

    prep_all_kernel<<<1088, 256, 0, stream>>>(
        xyz, feat, W1, W2, fT_hi, fT_lo, cellStart, sortedId, sortedXyz,
        W1x_hi, W1x_lo, W2x_hi, W2x_lo, out);
    fused_kernel<<<NGROUP / 4, 256, 0, stream>>>(
        xyz, cellStart, sortedId, sortedXyz, fT_hi, fT_lo,
        W1x_hi, W1x_lo, b1, W2x_hi, W2x_lo, b2, out);
}

// Round 6
// 169.357 us; speedup vs baseline: 2.2098x; 1.0526x over previous
//
#include <hip/hip_runtime.h>
#include <hip/hip_bf16.h>

#define B_      8
#define N_      8192
#define C_      64
#define H1_     64
#define H2_     128
#define NS      32
#define NPOINT  2048
#define NGROUP  (B_ * NPOINT)          // 16384
#define NXYZ    (B_ * NPOINT * 3)      // 49152
#define GD      10
#define NCP     1024                   // padded cell count (1000 used)

typedef short bf16x8 __attribute__((ext_vector_type(8)));
typedef float f32x4  __attribute__((ext_vector_type(4)));

#define MFMA32 __builtin_amdgcn_mfma_f32_16x16x32_bf16

__device__ inline unsigned short f2bf(float f) {        // HW RTNE cvt
    __hip_bfloat16 h = __float2bfloat16(f);
    return __builtin_bit_cast(unsigned short, h);
}
__device__ inline float bf2f(unsigned short h) {
    unsigned u = ((unsigned)h) << 16;
    return __builtin_bit_cast(float, u);
}

// Row permutation for the W1-output space (L1 rows / L2 k-cols):
// H'[p] = H_nat[n(p)] with n(p) chosen so that lane (cl,kq)'s L1 D-quadrant
// IS its L2 x32 B-fragment: n = (mt>>1)*32 + (rho>>2)*8 + ((mt&1)<<2) + (rho&3),
// p = mt*16 + rho.
__device__ __host__ inline int permrow(int p) {
    int mt = p >> 4, rho = p & 15;
    return ((mt >> 1) << 5) + ((rho >> 2) << 3) + ((mt & 1) << 2) + (rho & 3);
}

// ================================================================ K0: grid build (1 block/batch, 1024 thr)
__global__ __launch_bounds__(1024) void grid_kernel(
    const float* __restrict__ xyz,
    int* __restrict__ cellStart,     // [B][NCP+1]
    int* __restrict__ sortedId,      // [B][N]
    float* __restrict__ sortedXyz)   // [B][N][3]
{
    __shared__ int hist[NCP];
    __shared__ int wsum[16];
    int b = blockIdx.x, t = threadIdx.x;
    hist[t] = 0;
    __syncthreads();
    const float* base = xyz + (size_t)b * N_ * 3;
#pragma unroll
    for (int k = 0; k < N_ / 1024; ++k) {
        int i = k * 1024 + t;
        float x = base[i * 3], y = base[i * 3 + 1], z = base[i * 3 + 2];
        int c = (((int)(x * 9.999f)) * GD + (int)(y * 9.999f)) * GD + (int)(z * 9.999f);
        atomicAdd(&hist[c], 1);
    }
    __syncthreads();
    int s = hist[t];
    int lane = t & 63, w = t >> 6;
    int v = s;
    for (int d = 1; d < 64; d <<= 1) {
        int o = __shfl_up(v, d);
        if (lane >= d) v += o;
    }
    if (lane == 63) wsum[w] = v;
    __syncthreads();
    int wofs = 0;
#pragma unroll
    for (int i = 0; i < 16; ++i) wofs += (i < w) ? wsum[i] : 0;
    int excl = wofs + v - s;
    int* cs = cellStart + b * (NCP + 1);
    cs[t] = excl;
    if (t == 1023) cs[NCP] = excl + s;
    __syncthreads();
    hist[t] = excl;
    __syncthreads();
#pragma unroll
    for (int k = 0; k < N_ / 1024; ++k) {
        int i = k * 1024 + t;
        float x = base[i * 3], y = base[i * 3 + 1], z = base[i * 3 + 2];
        int c = (((int)(x * 9.999f)) * GD + (int)(y * 9.999f)) * GD + (int)(z * 9.999f);
        int pos = atomicAdd(&hist[c], 1);
        sortedId[b * N_ + pos] = i;
        float* d = sortedXyz + ((size_t)(b * N_) + pos) * 3;
        d[0] = x; d[1] = y; d[2] = z;
    }
}

// ================================================================ K1: prep
// blocks [0,1024): ftrans  (B,C,N) f32 -> (B,N,C) bf16 hi/lo
// blocks [1024,1048): new_xyz copy (float4)
// blocks [1048,1080): weight prep (hi/lo, MFMA-permuted, W1 rows permrow'd)
__global__ __launch_bounds__(256) void prep_all_kernel(
    const float* __restrict__ xyz, const float* __restrict__ feat,
    const float* __restrict__ W1, const float* __restrict__ W2,
    unsigned short* __restrict__ fT_hi, unsigned short* __restrict__ fT_lo,
    unsigned short* __restrict__ W1x_hi, unsigned short* __restrict__ W1x_lo,
    unsigned short* __restrict__ W2x_hi, unsigned short* __restrict__ W2x_lo,
    float* __restrict__ out)
{
    __shared__ float tile[64][65];
    int blk = blockIdx.x, t = threadIdx.x;

    if (blk < 1024) {
        // ---------------- ftrans
        int b = blk >> 7, nt = blk & 127;
        int n0 = nt * 64;
        int tx = t & 63, ty = t >> 6;
#pragma unroll
        for (int k = 0; k < 16; ++k) {
            int c = ty * 16 + k;
            tile[c][tx] = feat[((size_t)b * C_ + c) * N_ + n0 + tx];
        }
        __syncthreads();
#pragma unroll
        for (int k = 0; k < 16; ++k) {
            int n = ty * 16 + k;
            float v = tile[tx][n];
            unsigned short h = f2bf(v);
            size_t dst = ((size_t)(b * N_ + n0 + n)) * C_ + tx;
            fT_hi[dst] = h;
            fT_lo[dst] = f2bf(v - bf2f(h));
        }
    } else if (blk < 1048) {
        // ---------------- new_xyz copy (float4 granularity)
        const float4* src = reinterpret_cast<const float4*>(xyz);
        float4* dst = reinterpret_cast<float4*>(out);
#pragma unroll
        for (int k = 0; k < 2; ++k) {
            int i4 = (blk - 1024) * 512 + k * 256 + t;      // < 12288
            int b = i4 / 1536, r = i4 - b * 1536;
            dst[i4] = src[b * 6144 + r];
        }
    } else {
        // ---------------- weight prep
        int tg = (blk - 1048) * 256 + t;
        if (tg < 6144) {
            // W1x[(mt*3+kt)*512 + (kq*16+cl)*8 + j] <- W1nat[permrow(mt*16+cl)][k=kt*32+kq*8+j]
            int j = tg & 7, cl = (tg >> 3) & 15, kq = (tg >> 7) & 3, t2 = tg >> 9;
            int kt = t2 % 3, mt = t2 / 3;
            int row = permrow(mt * 16 + cl);
            int k = kt * 32 + kq * 8 + j;
            float wv = 0.f;
            if (k < 64) wv = W1[row * 67 + 3 + k];
            else if (k < 67) wv = W1[row * 67 + (k - 64)];
            unsigned short h = f2bf(wv);
            W1x_hi[tg] = h; W1x_lo[tg] = f2bf(wv - bf2f(h));
        }
        if (tg < 8192) {
            // W2x[(mt2*2+kt)*512 + (kq*16+cl)*8 + j] <- W2[mt2*16+cl][permrow-SPACE col kt*32+kq*8+j]
            // (columns are in H' space == natural index kt*32+kq*8+j by construction of permrow)
            int j = tg & 7, cl = (tg >> 3) & 15, kq = (tg >> 7) & 3;
            int kt = (tg >> 9) & 1, mt2 = tg >> 10;
            int row = mt2 * 16 + cl, k = kt * 32 + kq * 8 + j;
            float wv = W2[row * 64 + k];
            unsigned short h = f2bf(wv);
            W2x_hi[tg] = h; W2x_lo[tg] = f2bf(wv - bf2f(h));
        }
    }
}

// ================================================================ K2: fused ballq + MLP + maxpool + store
// Wave per group, 4 groups/block. L1 + L2 both 16x16x32 bf16 hi/lo split; the W1
// row-permutation makes each lane's relu'd L1 acc exactly its L2 x32 B-fragment.
__global__ __launch_bounds__(256) void fused_kernel(
    const float* __restrict__ xyz,
    const int* __restrict__ cellStart,
    const int* __restrict__ sortedId,
    const float* __restrict__ sortedXyz,
    const unsigned short* __restrict__ fT_hi, const unsigned short* __restrict__ fT_lo,
    const unsigned short* __restrict__ W1x_hi, const unsigned short* __restrict__ W1x_lo,
    const float* __restrict__ b1,
    const unsigned short* __restrict__ W2x_hi, const unsigned short* __restrict__ W2x_lo,
    const float* __restrict__ b2,
    float* __restrict__ out)
{
    __shared__ int shbuf[4][128];            // hitbuf (per-wave), then ystage (per-wave slice)
    int t = threadIdx.x;
    int w = t >> 6, lane = t & 63;
    int g = blockIdx.x * 4 + w;
    int b = g >> 11, s = g & 2047;

    // ---------------- ball query ----------------
    const float* qp = xyz + ((size_t)(b * N_) + s) * 3;
    float qx = qp[0], qy = qp[1], qz = qp[2];
    const float r2 = 0.01f;   // f32(0.1(f64)^2) == 0.01f exactly
    unsigned long long lmask = (1ull << lane) - 1ull;

    int cx = (int)(qx * 9.999f), cy = (int)(qy * 9.999f), cz = (int)(qz * 9.999f);
    int xlo = max(cx - 1, 0), xhi = min(cx + 1, GD - 1);
    int ylo = max(cy - 1, 0), yhi = min(cy + 1, GD - 1);
    int zlo = max(cz - 1, 0), zhi = min(cz + 1, GD - 1);
    int nx = xhi - xlo + 1, ny = yhi - ylo + 1;
    int nruns = nx * ny;                     // <= 9 contiguous z-runs

    const int* cs = cellStart + b * (NCP + 1);
    int start = 0, len = 0;
    if (lane < nruns) {
        int xi = xlo + lane / ny, yi = ylo + lane % ny;
        int cbase = (xi * GD + yi) * GD;
        start = cs[cbase + zlo];
        len = cs[cbase + zhi + 1] - start;
    }
    int v = len;
    for (int d = 1; d < 64; d <<= 1) {
        int o = __shfl_up(v, d);
        if (lane >= d) v += o;
    }
    int T = __shfl(v, 63);
    int excl = v - len;
    int ro[9], rs[9];
#pragma unroll
    for (int rr = 0; rr < 9; ++rr) {
        int oo = __shfl(excl, rr);
        int ss = __shfl(start, rr);
        bool live = rr < nruns;
        ro[rr] = live ? oo : 0x7fffffff;
        rs[rr] = live ? (ss - oo) : 0;
    }

    int cnt = 0;
    for (int k0 = 0; k0 < T; k0 += 64) {
        int pos = k0 + lane;
        bool valid = pos < T;
        int basev = rs[0];
#pragma unroll
        for (int rr = 1; rr < 9; ++rr)
            basev = (ro[rr] <= pos) ? rs[rr] : basev;
        float px = 1.e30f, py = 1.e30f, pz = 1.e30f;
        int pid = 0;
        if (valid) {
            int src = basev + pos;
            const float* pp = sortedXyz + ((size_t)(b * N_) + src) * 3;
            px = pp[0]; py = pp[1]; pz = pp[2];
            pid = sortedId[b * N_ + src];
        }
        // bit-exact reference arithmetic: no FMA, (dx^2+dy^2)+dz^2
        float dx = __fsub_rn(px, qx);
        float dy = __fsub_rn(py, qy);
        float dz = __fsub_rn(pz, qz);
        float d2 = __fadd_rn(__fadd_rn(__fmul_rn(dx, dx), __fmul_rn(dy, dy)),
                             __fmul_rn(dz, dz));
        bool pred = valid && (d2 < r2);
        unsigned long long m = __ballot(pred);
        if (pred) {
            int p = cnt + __builtin_popcountll(m & lmask);
            if (p < 128) shbuf[w][p] = pid;
        }
        cnt += __builtin_popcountll(m);
    }

    // 128-wide in-register bitonic sort ascending (INF pad)
    const int INF = 0x7fffffff;
    int v0 = (lane < cnt && lane < 128) ? shbuf[w][lane] : INF;
    int v1 = (lane + 64 < cnt) ? shbuf[w][lane + 64] : INF;
#pragma unroll
    for (int k = 2; k <= 128; k <<= 1) {
#pragma unroll
        for (int j = 64; j >= 1; j >>= 1) {
            if (j > (k >> 1)) continue;
            if (j == 64) {
                int lo = min(v0, v1), hi = max(v0, v1);
                v0 = lo; v1 = hi;
            } else {
                int p0 = __shfl_xor(v0, j), p1 = __shfl_xor(v1, j);
                bool lower = (lane & j) == 0;
                bool asc0 = (lane & k) == 0;
                bool asc1 = ((lane + 64) & k) == 0;
                v0 = (lower == asc0) ? min(v0, p0) : max(v0, p0);
                v1 = (lower == asc1) ? min(v1, p1) : max(v1, p1);
            }
        }
    }
    int first = __shfl(v0, 0);               // self always in ball -> cnt>=1
    int cl = lane & 15, kq = lane >> 4;
    int sv0 = __shfl(v0, cl);
    int sv1 = __shfl(v0, cl + 16);
    int i0 = (cl < cnt) ? sv0 : first;
    int i1 = (cl + 16 < cnt) ? sv1 : first;

    // ---------------- MLP ----------------
    bf16x8 bh[2][2], bl[2][2];
#pragma unroll
    for (int nt = 0; nt < 2; ++nt) {
        int i = nt ? i1 : i0;
        size_t rowoff = ((size_t)(b * N_ + i)) * C_ + kq * 8;
#pragma unroll
        for (int kt = 0; kt < 2; ++kt) {
            bh[nt][kt] = *reinterpret_cast<const bf16x8*>(fT_hi + rowoff + kt * 32);
            bl[nt][kt] = *reinterpret_cast<const bf16x8*>(fT_lo + rowoff + kt * 32);
        }
    }
    bf16x8 brel[2];
#pragma unroll
    for (int nt = 0; nt < 2; ++nt) {
        int i = nt ? i1 : i0;
        bf16x8 vv = (bf16x8)(short)0;
        if (kq == 0) {
            const float* p = xyz + ((size_t)(b * N_) + i) * 3;
            vv[0] = (short)f2bf(__fsub_rn(p[0], qx));
            vv[1] = (short)f2bf(__fsub_rn(p[1], qy));
            vv[2] = (short)f2bf(__fsub_rn(p[2], qz));
        }
        brel[nt] = vv;
    }

    // Layer 1: H'(64x32) = W1'(64x96) * X(96x32)   (rows in permrow space)
    f32x4 acc[4][2];
#pragma unroll
    for (int mt = 0; mt < 4; ++mt) {
        // bias rows for acc[mt], lane kq: natural base = (mt>>1)*32 + kq*8 + (mt&1)*4
        int bn = ((mt >> 1) << 5) + kq * 8 + ((mt & 1) << 2);
        f32x4 bias = *reinterpret_cast<const f32x4*>(b1 + bn);
        acc[mt][0] = bias;
        acc[mt][1] = bias;
    }
#pragma unroll
    for (int mt = 0; mt < 4; ++mt) {
        bf16x8 ah0 = *reinterpret_cast<const bf16x8*>(W1x_hi + (mt * 3 + 0) * 512 + lane * 8);
        bf16x8 ah1 = *reinterpret_cast<const bf16x8*>(W1x_hi + (mt * 3 + 1) * 512 + lane * 8);
        bf16x8 ah2 = *reinterpret_cast<const bf16x8*>(W1x_hi + (mt * 3 + 2) * 512 + lane * 8);
        bf16x8 al0 = *reinterpret_cast<const bf16x8*>(W1x_lo + (mt * 3 + 0) * 512 + lane * 8);
        bf16x8 al1 = *reinterpret_cast<const bf16x8*>(W1x_lo + (mt * 3 + 1) * 512 + lane * 8);
#pragma unroll
        for (int nt = 0; nt < 2; ++nt) {
            f32x4 a = acc[mt][nt];
            a = MFMA32(ah0, bh[nt][0], a, 0, 0, 0);
            a = MFMA32(ah0, bl[nt][0], a, 0, 0, 0);
            a = MFMA32(al0, bh[nt][0], a, 0, 0, 0);
            a = MFMA32(ah1, bh[nt][1], a, 0, 0, 0);
            a = MFMA32(ah1, bl[nt][1], a, 0, 0, 0);
            a = MFMA32(al1, bh[nt][1], a, 0, 0, 0);
            a = MFMA32(ah2, brel[nt], a, 0, 0, 0);
            acc[mt][nt] = a;
        }
    }

    // relu + hi/lo split IN-LANE -> L2 x32 B fragments (permrow makes this direct)
    bf16x8 p2h[2][2], p2l[2][2];
#pragma unroll
    for (int kt = 0; kt < 2; ++kt)
#pragma unroll
        for (int nt = 0; nt < 2; ++nt) {
            bf16x8 hh, hl;
#pragma unroll
            for (int i = 0; i < 4; ++i) {
                float va = fmaxf(acc[kt * 2 + 0][nt][i], 0.f);
                float vb = fmaxf(acc[kt * 2 + 1][nt][i], 0.f);
                unsigned short ha = f2bf(va), hb = f2bf(vb);
                hh[i]     = (short)ha;
                hh[4 + i] = (short)hb;
                hl[i]     = (short)f2bf(va - bf2f(ha));
                hl[4 + i] = (short)f2bf(vb - bf2f(hb));
            }
            p2h[kt][nt] = hh;
            p2l[kt][nt] = hl;
        }

    // Layer 2: Y(128x32) = W2'(128x64) * H'(64x32), two mt-halves
    float* ys = reinterpret_cast<float*>(&shbuf[0][0]);
#pragma unroll
    for (int hm = 0; hm < 2; ++hm) {
        f32x4 acc2[4][2];
#pragma unroll
        for (int mt4 = 0; mt4 < 4; ++mt4) {
            f32x4 bias = *reinterpret_cast<const f32x4*>(b2 + (hm * 4 + mt4) * 16 + kq * 4);
            acc2[mt4][0] = bias;
            acc2[mt4][1] = bias;
        }
#pragma unroll
        for (int mt4 = 0; mt4 < 4; ++mt4) {
            int mt2 = hm * 4 + mt4;
#pragma unroll
            for (int kt = 0; kt < 2; ++kt) {
                bf16x8 ah = *reinterpret_cast<const bf16x8*>(W2x_hi + (mt2 * 2 + kt) * 512 + lane * 8);
                bf16x8 al = *reinterpret_cast<const bf16x8*>(W2x_lo + (mt2 * 2 + kt) * 512 + lane * 8);
#pragma unroll
                for (int nt = 0; nt < 2; ++nt) {
                    f32x4 a = acc2[mt4][nt];
                    a = MFMA32(ah, p2h[kt][nt], a, 0, 0, 0);
                    a = MFMA32(ah, p2l[kt][nt], a, 0, 0, 0);
                    a = MFMA32(al, p2h[kt][nt], a, 0, 0, 0);
                    acc2[mt4][nt] = a;
                }
            }
        }
#pragma unroll
        for (int mt4 = 0; mt4 < 4; ++mt4) {
            f32x4 m;
#pragma unroll
            for (int r = 0; r < 4; ++r)
                m[r] = fmaxf(fmaxf(acc2[mt4][0][r], 0.f), fmaxf(acc2[mt4][1][r], 0.f));
#pragma unroll
            for (int mask = 1; mask <= 8; mask <<= 1)
#pragma unroll
                for (int r = 0; r < 4; ++r)
                    m[r] = fmaxf(m[r], __shfl_xor(m[r], mask));
            if (cl == 0)
                *reinterpret_cast<f32x4*>(ys + w * 128 + (hm * 4 + mt4) * 16 + kq * 4) = m;
        }
    }

    // ---------------- cooperative transposed store ----------------
    __syncthreads();
    if (t < 128) {
        int o = t;
        int bb = blockIdx.x >> 9;
        int s0 = (blockIdx.x & 511) * 4;
        float4 vv = { ys[0 * 128 + o], ys[1 * 128 + o], ys[2 * 128 + o], ys[3 * 128 + o] };
        *reinterpret_cast<float4*>(out + NXYZ + ((size_t)(bb * H2_ + o)) * NPOINT + s0) = vv;
    }
}

// ================================================================ launcher
extern "C" void kernel_launch(void* const* d_in, const int* in_sizes, int n_in,
                              void* d_out, int out_size, void* d_ws, size_t ws_size,
                              hipStream_t stream)
{
    const float* xyz  = (const float*)d_in[0];
    const float* feat = (const float*)d_in[1];
    const float* W1   = (const float*)d_in[2];
    const float* b1   = (const float*)d_in[3];
    const float* W2   = (const float*)d_in[4];
    const float* b2   = (const float*)d_in[5];
    float* out = (float*)d_out;

    char* ws = (char*)d_ws;
    size_t off = 0;
    unsigned short* W1x_hi = (unsigned short*)(ws + off);  off += 6144 * 2;
    unsigned short* W1x_lo = (unsigned short*)(ws + off);  off += 6144 * 2;
    unsigned short* W2x_hi = (unsigned short*)(ws + off);  off += 8192 * 2;
    unsigned short* W2x_lo = (unsigned short*)(ws + off);  off += 8192 * 2;
    off = (off + 255) & ~(size_t)255;
    int* cellStart = (int*)(ws + off);                     off += (size_t)B_ * (NCP + 1) * 4;
    int* sortedId = (int*)(ws + off);                      off += (size_t)B_ * N_ * 4;
    float* sortedXyz = (float*)(ws + off);                 off += (size_t)B_ * N_ * 3 * 4;
    off = (off + 255) & ~(size_t)255;
    unsigned short* fT_hi = (unsigned short*)(ws + off);   off += (size_t)B_ * N_ * C_ * 2;    // 8 MiB
    unsigned short* fT_lo = (unsigned short*)(ws + off);   off += (size_t)B_ * N_ * C_ * 2;    // 8 MiB

    grid_kernel<<<B_, 1024, 0, stream>>>(xyz, cellStart, sortedId, sortedXyz);
    prep_all_kernel<<<1080, 256, 0, stream>>>(
        xyz, feat, W1, W2, fT_hi, fT_lo, W1x_hi, W1x_lo, W2x_hi, W2x_lo, out);
    fused_kernel<<<NGROUP / 4, 256, 0, stream>>>(
        xyz, cellStart, sortedId, sortedXyz, fT_hi, fT_lo,
        W1x_hi, W1x_lo, b1, W2x_hi, W2x_lo, b2, out);
}